// Round 17
// baseline (118.374 us; speedup 1.0000x reference)
//
#include <hip/hip_runtime.h>

#define NB 4
#define NCI 64
#define NCO 64
#define PLANE 65536

// workspace offsets (in floats) — tables now computed in-kernel
#define OF_XS_RE 0
#define OF_XS_IM (OF_XS_RE + PLANE)
#define OF_O1_RE (OF_XS_IM + PLANE)
#define OF_O1_IM (OF_O1_RE + PLANE)
#define OF_O2_RE (OF_O1_IM + PLANE)
#define OF_O2_IM (OF_O2_RE + PLANE)

// stage1 LDS plane layout (per buffer)
#define XEOFF(w) ((w)*260)
#define XOOFF(w) (16*260 + 8 + (w)*260)

#define TPF 6.2831853071795864769f

// Fused stage 1+2, 1024 threads, grid 256 (R9 structure) with:
//  - DOUBLE-BUFFERED chunk staging: one barrier per chunk (was two)
//  - single-chunk register prefetch (8 VGPR, no ring -> no spill)
//  - trig tables computed in-kernel (k0 eliminated)
__global__ __launch_bounds__(1024) void k12_dft(const float* __restrict__ x,
                                                float* __restrict__ ws) {
  __shared__ float bufA[8336], bufB[8336];
  __shared__ float cst[256], snt[256];
  __shared__ float2 s2[1024];
  const int t = threadIdx.x;
  const int img = blockIdx.x;

  if (t < 256) {
    float sv_, cv_;
    sincosf(TPF * (float)t * (1.0f/256.0f), &sv_, &cv_);
    cst[t] = cv_;  snt[t] = sv_;
  }

  const int sl = t & 3, row = t >> 2;
  const int wq = t & 3, p = (t >> 2) & 1;
  const int kg = (t >> 3) & 1, tr = t >> 4;
  int kyv[4];
#pragma unroll
  for (int j = 0; j < 4; ++j) kyv[j] = p + 8*kg + 2*j;

  const float* xb = x + (size_t)img * 65536;

  // prologue: load + stage chunk 0 into bufA
  float4 lo = *(const float4*)(xb + row*256 + sl*4);
  float4 hi = *(const float4*)(xb + row*256 + 128 + sl*4);
  bufA[XEOFF(sl*4+0) + row] = lo.x + hi.x;
  bufA[XEOFF(sl*4+1) + row] = lo.y + hi.y;
  bufA[XEOFF(sl*4+2) + row] = lo.z + hi.z;
  bufA[XEOFF(sl*4+3) + row] = lo.w + hi.w;
  bufA[XOOFF(sl*4+0) + row] = lo.x - hi.x;
  bufA[XOOFF(sl*4+1) + row] = lo.y - hi.y;
  bufA[XOOFF(sl*4+2) + row] = lo.z - hi.z;
  bufA[XOOFF(sl*4+3) + row] = lo.w - hi.w;
  __syncthreads();                     // cst/snt + chunk 0 ready

  float cd[4], sd[4];
#pragma unroll
  for (int j = 0; j < 4; ++j) { cd[j] = cst[kyv[j]]; sd[j] = snt[kyv[j]]; }

  float ar[4][4], ai[4][4];
#pragma unroll
  for (int j = 0; j < 4; ++j)
#pragma unroll
    for (int r = 0; r < 4; ++r) { ar[j][r] = 0.f; ai[j][r] = 0.f; }

  const int pofs = p ? (16*260 + 8) : 0;

#pragma unroll
  for (int c = 0; c < 8; ++c) {
    float* cur = (c & 1) ? bufB : bufA;      // static under full unroll
    float* nxt = (c & 1) ? bufA : bufB;
    if (c < 7) {                             // issue next-chunk loads early
      const int w0n = (c+1) * 16;
      lo = *(const float4*)(xb + row*256 + w0n + sl*4);
      hi = *(const float4*)(xb + row*256 + w0n + 128 + sl*4);
    }
    // compute chunk c from cur
    float cc[4], sv[4];
#pragma unroll
    for (int j = 0; j < 4; ++j) {
      const int m = (kyv[j] * (c*16 + wq*4)) & 255;
      cc[j] = cst[m];
      sv[j] = snt[m];
    }
    const float* rp = cur + pofs;
#pragma unroll
    for (int i = 0; i < 4; ++i) {
      const int wl = wq*4 + i;
      const float4 xs4 = *(const float4*)&rp[wl*260 + tr*4];
#pragma unroll
      for (int j = 0; j < 4; ++j) {
        ar[j][0] += xs4.x * cc[j];  ai[j][0] -= xs4.x * sv[j];
        ar[j][1] += xs4.y * cc[j];  ai[j][1] -= xs4.y * sv[j];
        ar[j][2] += xs4.z * cc[j];  ai[j][2] -= xs4.z * sv[j];
        ar[j][3] += xs4.w * cc[j];  ai[j][3] -= xs4.w * sv[j];
        const float nc = cc[j]*cd[j] - sv[j]*sd[j];
        const float ns = sv[j]*cd[j] + cc[j]*sd[j];
        cc[j] = nc; sv[j] = ns;
      }
    }
    if (c < 7) {                             // stage chunk c+1 into nxt
      nxt[XEOFF(sl*4+0) + row] = lo.x + hi.x;
      nxt[XEOFF(sl*4+1) + row] = lo.y + hi.y;
      nxt[XEOFF(sl*4+2) + row] = lo.z + hi.z;
      nxt[XEOFF(sl*4+3) + row] = lo.w + hi.w;
      nxt[XOOFF(sl*4+0) + row] = lo.x - hi.x;
      nxt[XOOFF(sl*4+1) + row] = lo.y - hi.y;
      nxt[XOOFF(sl*4+2) + row] = lo.z - hi.z;
      nxt[XOOFF(sl*4+3) + row] = lo.w - hi.w;
    }
    __syncthreads();                         // ONE barrier per chunk
  }

#pragma unroll
  for (int j = 0; j < 4; ++j)
#pragma unroll
    for (int r = 0; r < 4; ++r) {
      ar[j][r] += __shfl_xor(ar[j][r], 1);
      ar[j][r] += __shfl_xor(ar[j][r], 2);
      ai[j][r] += __shfl_xor(ai[j][r], 1);
      ai[j][r] += __shfl_xor(ai[j][r], 2);
    }
  if (wq == 0) {                             // Xw planes into bufA
#pragma unroll
    for (int j = 0; j < 4; ++j) {
      const int ky = kyv[j];
      float4 sr; sr.x = ar[j][0]; sr.y = ar[j][1]; sr.z = ar[j][2]; sr.w = ar[j][3];
      float4 si; si.x = ai[j][0]; si.y = ai[j][1]; si.z = ai[j][2]; si.w = ai[j][3];
      *(float4*)&bufA[XEOFF(ky) + tr*4] = sr;
      *(float4*)&bufA[XOOFF(ky) + tr*4] = si;
    }
  }
  __syncthreads();

  // phase B: h-DFT, quarter h-range per thread
  const int ky2 = t & 15, kx = (t >> 4) & 15, hh = t >> 8;
  const float cdk = cst[kx], sdk = snt[kx];
  const int m0 = (kx * hh * 64) & 255;
  float cR = cst[m0], sR = snt[m0];
  float arr = 0.f, aii = 0.f;
  const int be = XEOFF(ky2) + hh*64;
  const int bo = XOOFF(ky2) + hh*64;
#pragma unroll 4
  for (int hq = 0; hq < 16; ++hq) {
    const float4 xr = *(const float4*)&bufA[be + hq*4];
    const float4 xi = *(const float4*)&bufA[bo + hq*4];
    {
      arr += xr.x*cR + xi.x*sR;  aii += xi.x*cR - xr.x*sR;
      const float nc = cR*cdk - sR*sdk, ns = sR*cdk + cR*sdk; cR = nc; sR = ns;
    }
    {
      arr += xr.y*cR + xi.y*sR;  aii += xi.y*cR - xr.y*sR;
      const float nc = cR*cdk - sR*sdk, ns = sR*cdk + cR*sdk; cR = nc; sR = ns;
    }
    {
      arr += xr.z*cR + xi.z*sR;  aii += xi.z*cR - xr.z*sR;
      const float nc = cR*cdk - sR*sdk, ns = sR*cdk + cR*sdk; cR = nc; sR = ns;
    }
    {
      arr += xr.w*cR + xi.w*sR;  aii += xi.w*cR - xr.w*sR;
      const float nc = cR*cdk - sR*sdk, ns = sR*cdk + cR*sdk; cR = nc; sR = ns;
    }
  }
  s2[t].x = arr; s2[t].y = aii;
  __syncthreads();
  if (t < 256) {
    float xre = s2[t].x + s2[t+256].x + s2[t+512].x + s2[t+768].x;
    float xim = s2[t].y + s2[t+256].y + s2[t+512].y + s2[t+768].y;
    ws[OF_XS_RE + img*256 + t] = xre;
    ws[OF_XS_IM + img*256 + t] = xim;
  }
}

// Stage 3: o1/o2[b,o,m] = sum_i xs[b,i,m] * (wr + i wi)[i,o,m]
__global__ __launch_bounds__(256) void k3_mix(const float* __restrict__ w1r,
    const float* __restrict__ w1i, const float* __restrict__ w2r,
    const float* __restrict__ w2i, float* __restrict__ ws) {
  const int o  = blockIdx.x;     // 0..63
  const int mc = blockIdx.y;     // 0..3
  const int t  = threadIdx.x;    // 256
  const int b  = t >> 6;
  const int m  = (mc << 6) + (t & 63);
  const float* xsr = ws + OF_XS_RE;
  const float* xsi = ws + OF_XS_IM;
  float a1r=0.f, a1i=0.f, a2r=0.f, a2i=0.f;
#pragma unroll 4
  for (int i = 0; i < NCI; ++i) {
    const float xr = xsr[((b*NCI + i) << 8) + m];
    const float xi = xsi[((b*NCI + i) << 8) + m];
    const int wi = ((i*NCO + o) << 8) + m;
    const float p = w1r[wi], q = w1i[wi], u = w2r[wi], v = w2i[wi];
    a1r += xr*p - xi*q;
    a1i += xr*q + xi*p;
    a2r += xr*u - xi*v;
    a2i += xr*v + xi*u;
  }
  const int oi = ((b*NCO + o) << 8) + m;
  ws[OF_O1_RE + oi] = a1r;
  ws[OF_O1_IM + oi] = a1i;
  ws[OF_O2_RE + oi] = a2r;
  ws[OF_O2_IM + oi] = a2i;
}

// Fused stage 4+5 (R13 structure; trig tables computed in-kernel).
__global__ __launch_bounds__(256) void k45_idft(const float* __restrict__ ws,
                                                float* __restrict__ out) {
  __shared__ __align__(16) float o1r[256], o1i[256], o2r[256], o2i[256];
  __shared__ float cst[256], snt[256];
  __shared__ __align__(16) float Sr[64][20], Si[64][20];
  const int t  = threadIdx.x;
  const int bo = blockIdx.x >> 2;
  const int hc = blockIdx.x & 3;

  o1r[t] = ws[OF_O1_RE + bo*256 + t];
  o1i[t] = ws[OF_O1_IM + bo*256 + t];
  o2r[t] = ws[OF_O2_RE + bo*256 + t];
  o2i[t] = ws[OF_O2_IM + bo*256 + t];
  {
    float sv_, cv_;
    sincosf(TPF * (float)t * (1.0f/256.0f), &sv_, &cv_);
    cst[t] = cv_;  snt[t] = sv_;
  }
  __syncthreads();

  const int wl = t & 31;
  float c[15], s[15], c2[15], s2[15];
#pragma unroll
  for (int k = 0; k < 15; ++k) {
    const int mi = ((k+1) * wl) & 255;
    c[k] = cst[mi];
    s[k] = snt[mi];
  }
  {
    const float R = 0.70710678118654752f;
#pragma unroll
    for (int k = 0; k < 15; ++k) {
      const int r8 = (k + 1) & 7;
      switch (r8) {
        case 0: c2[k] =  c[k];            s2[k] =  s[k];            break;
        case 1: c2[k] = (c[k]-s[k])*R;    s2[k] = (s[k]+c[k])*R;    break;
        case 2: c2[k] = -s[k];            s2[k] =  c[k];            break;
        case 3: c2[k] = -(c[k]+s[k])*R;   s2[k] = (c[k]-s[k])*R;    break;
        case 4: c2[k] = -c[k];            s2[k] = -s[k];            break;
        case 5: c2[k] = (s[k]-c[k])*R;    s2[k] = -(c[k]+s[k])*R;   break;
        case 6: c2[k] =  s[k];            s2[k] = -c[k];            break;
        default:c2[k] = (c[k]+s[k])*R;    s2[k] = (s[k]-c[k])*R;    break;
      }
    }
  }

  // ---- phase A ----
  {
    const int hl = t >> 2, kq = t & 3;
    const int h  = hc*64 + hl;
    const float chh = cst[h], shh = snt[h];
    float c1 = 1.f, s1 = 0.f;
    const int m2i = (240 * h) & 255;
    float cB = cst[m2i], sB = snt[m2i];
    float4 sr = {0.f,0.f,0.f,0.f}, si = {0.f,0.f,0.f,0.f};
    for (int j = 0; j < 16; ++j) {
      const float4 r1 = *(const float4*)&o1r[j*16 + kq*4];
      const float4 i1 = *(const float4*)&o1i[j*16 + kq*4];
      const float4 r2 = *(const float4*)&o2r[j*16 + kq*4];
      const float4 i2 = *(const float4*)&o2i[j*16 + kq*4];
      sr.x += r1.x*c1 - i1.x*s1 + r2.x*cB - i2.x*sB;
      si.x += r1.x*s1 + i1.x*c1 + r2.x*sB + i2.x*cB;
      sr.y += r1.y*c1 - i1.y*s1 + r2.y*cB - i2.y*sB;
      si.y += r1.y*s1 + i1.y*c1 + r2.y*sB + i2.y*cB;
      sr.z += r1.z*c1 - i1.z*s1 + r2.z*cB - i2.z*sB;
      si.z += r1.z*s1 + i1.z*c1 + r2.z*sB + i2.z*cB;
      sr.w += r1.w*c1 - i1.w*s1 + r2.w*cB - i2.w*sB;
      si.w += r1.w*s1 + i1.w*c1 + r2.w*sB + i2.w*cB;
      const float n1c = c1*chh - s1*shh, n1s = s1*chh + c1*shh;
      const float n2c = cB*chh - sB*shh, n2s = sB*chh + cB*shh;
      c1 = n1c; s1 = n1s; cB = n2c; sB = n2s;
    }
    *(float4*)&Sr[hl][kq*4] = sr;
    *(float4*)&Si[hl][kq*4] = si;
  }
  __syncthreads();

  // ---- phase B: row-paired, radix-4 butterfly x2 trig sets ----
  const int half = (t >> 5) & 1;
  const int wv = t >> 6;
  const float scale = 2.0f / 65536.0f;
  const size_t tilebase = ((size_t)bo*256 + hc*64) * 256;
#pragma unroll 2
  for (int pr = 0; pr < 8; ++pr) {
    const int hl = wv*16 + pr*2 + half;
    const float4 a0 = *(const float4*)&Sr[hl][0];
    const float4 a1 = *(const float4*)&Sr[hl][4];
    const float4 a2 = *(const float4*)&Sr[hl][8];
    const float4 a3 = *(const float4*)&Sr[hl][12];
    const float4 b0 = *(const float4*)&Si[hl][0];
    const float4 b1 = *(const float4*)&Si[hl][4];
    const float4 b2 = *(const float4*)&Si[hl][8];
    const float4 b3 = *(const float4*)&Si[hl][12];
    const float re[16] = {a0.x,a0.y,a0.z,a0.w, a1.x,a1.y,a1.z,a1.w,
                          a2.x,a2.y,a2.z,a2.w, a3.x,a3.y,a3.z,a3.w};
    const float im[16] = {b0.x,b0.y,b0.z,b0.w, b1.x,b1.y,b1.z,b1.w,
                          b2.x,b2.y,b2.z,b2.w, b3.x,b3.y,b3.z,b3.w};
    const size_t ob = tilebase + (size_t)hl*256;

#pragma unroll
    for (int g = 0; g < 2; ++g) {
      const float* cc = g ? c2 : c;
      const float* ss = g ? s2 : s;
      float PA = 0.5f * re[0];
      float PB = 0.f, PC = 0.f, PD = 0.f, QB = 0.f, QD = 0.f;
#pragma unroll
      for (int k = 0; k < 15; ++k) {
        const int ky = k + 1;
        const float R = re[ky], I = im[ky];
        const int cls = ky & 3;
        if (cls == 0)      PA += R*cc[k] - I*ss[k];
        else if (cls == 1) { PB += R*cc[k] - I*ss[k];  QB += R*ss[k] + I*cc[k]; }
        else if (cls == 2) PC += R*cc[k] - I*ss[k];
        else               { PD += R*cc[k] - I*ss[k];  QD += R*ss[k] + I*cc[k]; }
      }
      const float T1 = PA + PC, T2 = PB + PD;
      const float T3 = PA - PC, T4 = QB - QD;
      const int cb = wl + g*32;
      out[ob + cb]       = (T1 + T2) * scale;
      out[ob + cb + 64]  = (T3 - T4) * scale;
      out[ob + cb + 128] = (T1 - T2) * scale;
      out[ob + cb + 192] = (T3 + T4) * scale;
    }
  }
}

extern "C" void kernel_launch(void* const* d_in, const int* in_sizes, int n_in,
                              void* d_out, int out_size, void* d_ws, size_t ws_size,
                              hipStream_t stream) {
  const float* x   = (const float*)d_in[0];
  const float* w1r = (const float*)d_in[1];
  const float* w1i = (const float*)d_in[2];
  const float* w2r = (const float*)d_in[3];
  const float* w2i = (const float*)d_in[4];
  float* out = (float*)d_out;
  float* ws  = (float*)d_ws;

  hipLaunchKernelGGL(k12_dft,  dim3(256),   dim3(1024), 0, stream, x, ws);
  hipLaunchKernelGGL(k3_mix,   dim3(64, 4), dim3(256),  0, stream, w1r, w1i, w2r, w2i, ws);
  hipLaunchKernelGGL(k45_idft, dim3(1024),  dim3(256),  0, stream, ws, out);
}

// Round 18
// 64.141 us; speedup vs baseline: 1.8455x; 1.8455x over previous
//
#include <hip/hip_runtime.h>

#define NB 4
#define NCI 64
#define NCO 64
#define PLANE 65536

// workspace offsets (in floats)
#define OF_COS 0
#define OF_SIN 256
#define OF_TW  512                      // [30][256] k45 trig (ky=1..15 cos/sin)
#define OF_XS_RE (16384 + 32*PLANE)
#define OF_XS_IM (OF_XS_RE + PLANE)
#define OF_O1_RE (OF_XS_IM + PLANE)
#define OF_O1_IM (OF_O1_RE + PLANE)
#define OF_O2_RE (OF_O1_IM + PLANE)
#define OF_O2_IM (OF_O2_RE + PLANE)

// stage1 LDS plane layout (per buffer)
#define XEOFF(w) ((w)*260)
#define XOOFF(w) (16*260 + 8 + (w)*260)

// grid 31: block 0 -> cos/sin tables; blocks 1..30 -> one TW row each
__global__ __launch_bounds__(256) void k0_init(float* __restrict__ ws) {
  const int t = threadIdx.x, b = blockIdx.x;
  const double TP = 6.283185307179586;
  if (b == 0) {
    double a = TP * t / 256.0;
    ws[OF_COS + t] = (float)cos(a);
    ws[OF_SIN + t] = (float)sin(a);
  } else {
    const int p = b - 1;              // 0..29
    const int ky = (p >> 1) + 1;
    double a = TP * ((ky * t) & 255) / 256.0;
    ws[OF_TW + p*256 + t] = (p & 1) ? (float)sin(a) : (float)cos(a);
  }
}

// Fused stage 1+2, 1024 threads, grid 256 — R9 structure with DOUBLE-BUFFERED
// chunk staging in a ROLLED loop (R16/R17 lesson: unrolling this loop spills).
// One barrier per chunk (10 total, was 17); next-chunk loads issue before
// compute; staging lands in the other buffer after compute.
__global__ __launch_bounds__(1024) void k12_dft(const float* __restrict__ x,
                                                float* __restrict__ ws) {
  __shared__ float bufA[8336], bufB[8336];
  __shared__ float cst[256], snt[256];
  __shared__ float2 s2[1024];
  const int t = threadIdx.x;
  const int img = blockIdx.x;

  if (t < 256) { cst[t] = ws[OF_COS + t]; snt[t] = ws[OF_SIN + t]; }

  const int sl = t & 3, row = t >> 2;
  const int wq = t & 3, p = (t >> 2) & 1;
  const int kg = (t >> 3) & 1, tr = t >> 4;
  int kyv[4];
#pragma unroll
  for (int j = 0; j < 4; ++j) kyv[j] = p + 8*kg + 2*j;

  const float* xb = x + (size_t)img * 65536;

  // prologue: issue chunk-0 loads
  float4 lo = *(const float4*)(xb + row*256 + sl*4);
  float4 hi = *(const float4*)(xb + row*256 + 128 + sl*4);

  __syncthreads();                     // cst/snt ready

  float cd[4], sd[4];
#pragma unroll
  for (int j = 0; j < 4; ++j) { cd[j] = cst[kyv[j]]; sd[j] = snt[kyv[j]]; }

  float ar[4][4], ai[4][4];
#pragma unroll
  for (int j = 0; j < 4; ++j)
#pragma unroll
    for (int r = 0; r < 4; ++r) { ar[j][r] = 0.f; ai[j][r] = 0.f; }

  // stage chunk 0 into bufA
  bufA[XEOFF(sl*4+0) + row] = lo.x + hi.x;
  bufA[XEOFF(sl*4+1) + row] = lo.y + hi.y;
  bufA[XEOFF(sl*4+2) + row] = lo.z + hi.z;
  bufA[XEOFF(sl*4+3) + row] = lo.w + hi.w;
  bufA[XOOFF(sl*4+0) + row] = lo.x - hi.x;
  bufA[XOOFF(sl*4+1) + row] = lo.y - hi.y;
  bufA[XOOFF(sl*4+2) + row] = lo.z - hi.z;
  bufA[XOOFF(sl*4+3) + row] = lo.w - hi.w;
  __syncthreads();                     // chunk 0 staged

  const int pofs = p ? (16*260 + 8) : 0;

  for (int c = 0; c < 8; ++c) {        // ROLLED — do not unroll (spill)
    float* cur = (c & 1) ? bufB : bufA;
    float* nxt = (c & 1) ? bufA : bufB;
    if (c < 7) {                       // issue next-chunk loads early
      const int w0n = (c+1) * 16;
      lo = *(const float4*)(xb + row*256 + w0n + sl*4);
      hi = *(const float4*)(xb + row*256 + w0n + 128 + sl*4);
    }
    // compute chunk c from cur
    float cc[4], sv[4];
#pragma unroll
    for (int j = 0; j < 4; ++j) {
      const int m = (kyv[j] * (c*16 + wq*4)) & 255;
      cc[j] = cst[m];
      sv[j] = snt[m];
    }
    const float* rp = cur + pofs;
#pragma unroll
    for (int i = 0; i < 4; ++i) {
      const int wl = wq*4 + i;
      const float4 xs4 = *(const float4*)&rp[wl*260 + tr*4];
#pragma unroll
      for (int j = 0; j < 4; ++j) {
        ar[j][0] += xs4.x * cc[j];  ai[j][0] -= xs4.x * sv[j];
        ar[j][1] += xs4.y * cc[j];  ai[j][1] -= xs4.y * sv[j];
        ar[j][2] += xs4.z * cc[j];  ai[j][2] -= xs4.z * sv[j];
        ar[j][3] += xs4.w * cc[j];  ai[j][3] -= xs4.w * sv[j];
        const float nc = cc[j]*cd[j] - sv[j]*sd[j];
        const float ns = sv[j]*cd[j] + cc[j]*sd[j];
        cc[j] = nc; sv[j] = ns;
      }
    }
    if (c < 7) {                       // stage chunk c+1 into nxt
      nxt[XEOFF(sl*4+0) + row] = lo.x + hi.x;
      nxt[XEOFF(sl*4+1) + row] = lo.y + hi.y;
      nxt[XEOFF(sl*4+2) + row] = lo.z + hi.z;
      nxt[XEOFF(sl*4+3) + row] = lo.w + hi.w;
      nxt[XOOFF(sl*4+0) + row] = lo.x - hi.x;
      nxt[XOOFF(sl*4+1) + row] = lo.y - hi.y;
      nxt[XOOFF(sl*4+2) + row] = lo.z - hi.z;
      nxt[XOOFF(sl*4+3) + row] = lo.w - hi.w;
    }
    __syncthreads();                   // ONE barrier per chunk
  }

#pragma unroll
  for (int j = 0; j < 4; ++j)
#pragma unroll
    for (int r = 0; r < 4; ++r) {
      ar[j][r] += __shfl_xor(ar[j][r], 1);
      ar[j][r] += __shfl_xor(ar[j][r], 2);
      ai[j][r] += __shfl_xor(ai[j][r], 1);
      ai[j][r] += __shfl_xor(ai[j][r], 2);
    }
  if (wq == 0) {                       // Xw planes into bufA
#pragma unroll
    for (int j = 0; j < 4; ++j) {
      const int ky = kyv[j];
      float4 sr; sr.x = ar[j][0]; sr.y = ar[j][1]; sr.z = ar[j][2]; sr.w = ar[j][3];
      float4 si; si.x = ai[j][0]; si.y = ai[j][1]; si.z = ai[j][2]; si.w = ai[j][3];
      *(float4*)&bufA[XEOFF(ky) + tr*4] = sr;
      *(float4*)&bufA[XOOFF(ky) + tr*4] = si;
    }
  }
  __syncthreads();

  // phase B: h-DFT, quarter h-range per thread
  const int ky2 = t & 15, kx = (t >> 4) & 15, hh = t >> 8;
  const float cdk = cst[kx], sdk = snt[kx];
  const int m0 = (kx * hh * 64) & 255;
  float cR = cst[m0], sR = snt[m0];
  float arr = 0.f, aii = 0.f;
  const int be = XEOFF(ky2) + hh*64;
  const int bo = XOOFF(ky2) + hh*64;
#pragma unroll 4
  for (int hq = 0; hq < 16; ++hq) {
    const float4 xr = *(const float4*)&bufA[be + hq*4];
    const float4 xi = *(const float4*)&bufA[bo + hq*4];
    {
      arr += xr.x*cR + xi.x*sR;  aii += xi.x*cR - xr.x*sR;
      const float nc = cR*cdk - sR*sdk, ns = sR*cdk + cR*sdk; cR = nc; sR = ns;
    }
    {
      arr += xr.y*cR + xi.y*sR;  aii += xi.y*cR - xr.y*sR;
      const float nc = cR*cdk - sR*sdk, ns = sR*cdk + cR*sdk; cR = nc; sR = ns;
    }
    {
      arr += xr.z*cR + xi.z*sR;  aii += xi.z*cR - xr.z*sR;
      const float nc = cR*cdk - sR*sdk, ns = sR*cdk + cR*sdk; cR = nc; sR = ns;
    }
    {
      arr += xr.w*cR + xi.w*sR;  aii += xi.w*cR - xr.w*sR;
      const float nc = cR*cdk - sR*sdk, ns = sR*cdk + cR*sdk; cR = nc; sR = ns;
    }
  }
  s2[t].x = arr; s2[t].y = aii;
  __syncthreads();
  if (t < 256) {
    float xre = s2[t].x + s2[t+256].x + s2[t+512].x + s2[t+768].x;
    float xim = s2[t].y + s2[t+256].y + s2[t+512].y + s2[t+768].y;
    ws[OF_XS_RE + img*256 + t] = xre;
    ws[OF_XS_IM + img*256 + t] = xim;
  }
}

// Stage 3: o1/o2[b,o,m] = sum_i xs[b,i,m] * (wr + i wi)[i,o,m]
__global__ __launch_bounds__(256) void k3_mix(const float* __restrict__ w1r,
    const float* __restrict__ w1i, const float* __restrict__ w2r,
    const float* __restrict__ w2i, float* __restrict__ ws) {
  const int o  = blockIdx.x;     // 0..63
  const int mc = blockIdx.y;     // 0..3
  const int t  = threadIdx.x;    // 256
  const int b  = t >> 6;
  const int m  = (mc << 6) + (t & 63);
  const float* xsr = ws + OF_XS_RE;
  const float* xsi = ws + OF_XS_IM;
  float a1r=0.f, a1i=0.f, a2r=0.f, a2i=0.f;
#pragma unroll 4
  for (int i = 0; i < NCI; ++i) {
    const float xr = xsr[((b*NCI + i) << 8) + m];
    const float xi = xsi[((b*NCI + i) << 8) + m];
    const int wi = ((i*NCO + o) << 8) + m;
    const float p = w1r[wi], q = w1i[wi], u = w2r[wi], v = w2i[wi];
    a1r += xr*p - xi*q;
    a1i += xr*q + xi*p;
    a2r += xr*u - xi*v;
    a2i += xr*v + xi*u;
  }
  const int oi = ((b*NCO + o) << 8) + m;
  ws[OF_O1_RE + oi] = a1r;
  ws[OF_O1_IM + oi] = a1i;
  ws[OF_O2_RE + oi] = a2r;
  ws[OF_O2_IM + oi] = a2i;
}

// Fused stage 4+5 (R13-verbatim, best measured).
__global__ __launch_bounds__(256) void k45_idft(const float* __restrict__ ws,
                                                float* __restrict__ out) {
  __shared__ __align__(16) float o1r[256], o1i[256], o2r[256], o2i[256];
  __shared__ float cst[256], snt[256];
  __shared__ __align__(16) float Sr[64][20], Si[64][20];
  const int t  = threadIdx.x;
  const int bo = blockIdx.x >> 2;
  const int hc = blockIdx.x & 3;

  o1r[t] = ws[OF_O1_RE + bo*256 + t];
  o1i[t] = ws[OF_O1_IM + bo*256 + t];
  o2r[t] = ws[OF_O2_RE + bo*256 + t];
  o2i[t] = ws[OF_O2_IM + bo*256 + t];
  cst[t] = ws[OF_COS + t];
  snt[t] = ws[OF_SIN + t];

  const int wl = t & 31;
  const float* Tw = ws + OF_TW;
  float c[15], s[15], c2[15], s2[15];
#pragma unroll
  for (int k = 0; k < 15; ++k) {
    c[k] = Tw[(2*k)*256 + wl];
    s[k] = Tw[(2*k+1)*256 + wl];
  }
  {
    const float R = 0.70710678118654752f;
#pragma unroll
    for (int k = 0; k < 15; ++k) {
      const int r8 = (k + 1) & 7;
      switch (r8) {
        case 0: c2[k] =  c[k];            s2[k] =  s[k];            break;
        case 1: c2[k] = (c[k]-s[k])*R;    s2[k] = (s[k]+c[k])*R;    break;
        case 2: c2[k] = -s[k];            s2[k] =  c[k];            break;
        case 3: c2[k] = -(c[k]+s[k])*R;   s2[k] = (c[k]-s[k])*R;    break;
        case 4: c2[k] = -c[k];            s2[k] = -s[k];            break;
        case 5: c2[k] = (s[k]-c[k])*R;    s2[k] = -(c[k]+s[k])*R;   break;
        case 6: c2[k] =  s[k];            s2[k] = -c[k];            break;
        default:c2[k] = (c[k]+s[k])*R;    s2[k] = (s[k]-c[k])*R;    break;
      }
    }
  }
  __syncthreads();

  // ---- phase A ----
  {
    const int hl = t >> 2, kq = t & 3;
    const int h  = hc*64 + hl;
    const float chh = cst[h], shh = snt[h];
    float c1 = 1.f, s1 = 0.f;
    const int m2i = (240 * h) & 255;
    float cB = cst[m2i], sB = snt[m2i];
    float4 sr = {0.f,0.f,0.f,0.f}, si = {0.f,0.f,0.f,0.f};
    for (int j = 0; j < 16; ++j) {
      const float4 r1 = *(const float4*)&o1r[j*16 + kq*4];
      const float4 i1 = *(const float4*)&o1i[j*16 + kq*4];
      const float4 r2 = *(const float4*)&o2r[j*16 + kq*4];
      const float4 i2 = *(const float4*)&o2i[j*16 + kq*4];
      sr.x += r1.x*c1 - i1.x*s1 + r2.x*cB - i2.x*sB;
      si.x += r1.x*s1 + i1.x*c1 + r2.x*sB + i2.x*cB;
      sr.y += r1.y*c1 - i1.y*s1 + r2.y*cB - i2.y*sB;
      si.y += r1.y*s1 + i1.y*c1 + r2.y*sB + i2.y*cB;
      sr.z += r1.z*c1 - i1.z*s1 + r2.z*cB - i2.z*sB;
      si.z += r1.z*s1 + i1.z*c1 + r2.z*sB + i2.z*cB;
      sr.w += r1.w*c1 - i1.w*s1 + r2.w*cB - i2.w*sB;
      si.w += r1.w*s1 + i1.w*c1 + r2.w*sB + i2.w*cB;
      const float n1c = c1*chh - s1*shh, n1s = s1*chh + c1*shh;
      const float n2c = cB*chh - sB*shh, n2s = sB*chh + cB*shh;
      c1 = n1c; s1 = n1s; cB = n2c; sB = n2s;
    }
    *(float4*)&Sr[hl][kq*4] = sr;
    *(float4*)&Si[hl][kq*4] = si;
  }
  __syncthreads();

  // ---- phase B: row-paired, radix-4 butterfly x2 trig sets ----
  const int half = (t >> 5) & 1;
  const int wv = t >> 6;
  const float scale = 2.0f / 65536.0f;
  const size_t tilebase = ((size_t)bo*256 + hc*64) * 256;
#pragma unroll 2
  for (int pr = 0; pr < 8; ++pr) {
    const int hl = wv*16 + pr*2 + half;
    const float4 a0 = *(const float4*)&Sr[hl][0];
    const float4 a1 = *(const float4*)&Sr[hl][4];
    const float4 a2 = *(const float4*)&Sr[hl][8];
    const float4 a3 = *(const float4*)&Sr[hl][12];
    const float4 b0 = *(const float4*)&Si[hl][0];
    const float4 b1 = *(const float4*)&Si[hl][4];
    const float4 b2 = *(const float4*)&Si[hl][8];
    const float4 b3 = *(const float4*)&Si[hl][12];
    const float re[16] = {a0.x,a0.y,a0.z,a0.w, a1.x,a1.y,a1.z,a1.w,
                          a2.x,a2.y,a2.z,a2.w, a3.x,a3.y,a3.z,a3.w};
    const float im[16] = {b0.x,b0.y,b0.z,b0.w, b1.x,b1.y,b1.z,b1.w,
                          b2.x,b2.y,b2.z,b2.w, b3.x,b3.y,b3.z,b3.w};
    const size_t ob = tilebase + (size_t)hl*256;

#pragma unroll
    for (int g = 0; g < 2; ++g) {
      const float* cc = g ? c2 : c;
      const float* ss = g ? s2 : s;
      float PA = 0.5f * re[0];
      float PB = 0.f, PC = 0.f, PD = 0.f, QB = 0.f, QD = 0.f;
#pragma unroll
      for (int k = 0; k < 15; ++k) {
        const int ky = k + 1;
        const float R = re[ky], I = im[ky];
        const int cls = ky & 3;
        if (cls == 0)      PA += R*cc[k] - I*ss[k];
        else if (cls == 1) { PB += R*cc[k] - I*ss[k];  QB += R*ss[k] + I*cc[k]; }
        else if (cls == 2) PC += R*cc[k] - I*ss[k];
        else               { PD += R*cc[k] - I*ss[k];  QD += R*ss[k] + I*cc[k]; }
      }
      const float T1 = PA + PC, T2 = PB + PD;
      const float T3 = PA - PC, T4 = QB - QD;
      const int cb = wl + g*32;
      out[ob + cb]       = (T1 + T2) * scale;
      out[ob + cb + 64]  = (T3 - T4) * scale;
      out[ob + cb + 128] = (T1 - T2) * scale;
      out[ob + cb + 192] = (T3 + T4) * scale;
    }
  }
}

extern "C" void kernel_launch(void* const* d_in, const int* in_sizes, int n_in,
                              void* d_out, int out_size, void* d_ws, size_t ws_size,
                              hipStream_t stream) {
  const float* x   = (const float*)d_in[0];
  const float* w1r = (const float*)d_in[1];
  const float* w1i = (const float*)d_in[2];
  const float* w2r = (const float*)d_in[3];
  const float* w2i = (const float*)d_in[4];
  float* out = (float*)d_out;
  float* ws  = (float*)d_ws;

  hipLaunchKernelGGL(k0_init,  dim3(31),    dim3(256),  0, stream, ws);
  hipLaunchKernelGGL(k12_dft,  dim3(256),   dim3(1024), 0, stream, x, ws);
  hipLaunchKernelGGL(k3_mix,   dim3(64, 4), dim3(256),  0, stream, w1r, w1i, w2r, w2i, ws);
  hipLaunchKernelGGL(k45_idft, dim3(1024),  dim3(256),  0, stream, ws, out);
}

// Round 19
// 60.506 us; speedup vs baseline: 1.9564x; 1.0601x over previous
//
#include <hip/hip_runtime.h>

#define NB 4
#define NCI 64
#define NCO 64
#define PLANE 65536

// workspace offsets (in floats) — trig tables computed in-kernel now
#define OF_XS_RE 0
#define OF_XS_IM (OF_XS_RE + PLANE)
#define OF_O1_RE (OF_XS_IM + PLANE)
#define OF_O1_IM (OF_O1_RE + PLANE)
#define OF_O2_RE (OF_O1_IM + PLANE)
#define OF_O2_IM (OF_O2_RE + PLANE)

// stage1 LDS plane layout (per buffer)
#define XEOFF(w) ((w)*260)
#define XOOFF(w) (16*260 + 8 + (w)*260)

#define TPF 6.2831853071795864769f

// Fused stage 1+2, 1024 threads, grid 256 — R18 structure (rolled dbuf chunk
// loop, one barrier per chunk) with:
//  - __launch_bounds__(1024,4): grant full 128-VGPR budget (R17 lesson:
//    default heuristic capped at 64 and spilled)
//  - trig tables via sincosf (k0 eliminated)
__global__ __launch_bounds__(1024, 4) void k12_dft(const float* __restrict__ x,
                                                   float* __restrict__ ws) {
  __shared__ float bufA[8336], bufB[8336];
  __shared__ float cst[256], snt[256];
  __shared__ float2 s2[1024];
  const int t = threadIdx.x;
  const int img = blockIdx.x;

  if (t < 256) {
    float sv_, cv_;
    sincosf(TPF * (float)t * (1.0f/256.0f), &sv_, &cv_);
    cst[t] = cv_;  snt[t] = sv_;
  }

  const int sl = t & 3, row = t >> 2;
  const int wq = t & 3, p = (t >> 2) & 1;
  const int kg = (t >> 3) & 1, tr = t >> 4;
  int kyv[4];
#pragma unroll
  for (int j = 0; j < 4; ++j) kyv[j] = p + 8*kg + 2*j;

  const float* xb = x + (size_t)img * 65536;

  // prologue: issue chunk-0 loads
  float4 lo = *(const float4*)(xb + row*256 + sl*4);
  float4 hi = *(const float4*)(xb + row*256 + 128 + sl*4);

  __syncthreads();                     // cst/snt ready

  float cd[4], sd[4];
#pragma unroll
  for (int j = 0; j < 4; ++j) { cd[j] = cst[kyv[j]]; sd[j] = snt[kyv[j]]; }

  float ar[4][4], ai[4][4];
#pragma unroll
  for (int j = 0; j < 4; ++j)
#pragma unroll
    for (int r = 0; r < 4; ++r) { ar[j][r] = 0.f; ai[j][r] = 0.f; }

  // stage chunk 0 into bufA
  bufA[XEOFF(sl*4+0) + row] = lo.x + hi.x;
  bufA[XEOFF(sl*4+1) + row] = lo.y + hi.y;
  bufA[XEOFF(sl*4+2) + row] = lo.z + hi.z;
  bufA[XEOFF(sl*4+3) + row] = lo.w + hi.w;
  bufA[XOOFF(sl*4+0) + row] = lo.x - hi.x;
  bufA[XOOFF(sl*4+1) + row] = lo.y - hi.y;
  bufA[XOOFF(sl*4+2) + row] = lo.z - hi.z;
  bufA[XOOFF(sl*4+3) + row] = lo.w - hi.w;
  __syncthreads();                     // chunk 0 staged

  const int pofs = p ? (16*260 + 8) : 0;

  for (int c = 0; c < 8; ++c) {        // ROLLED — do not unroll (spill)
    float* cur = (c & 1) ? bufB : bufA;
    float* nxt = (c & 1) ? bufA : bufB;
    if (c < 7) {                       // issue next-chunk loads early
      const int w0n = (c+1) * 16;
      lo = *(const float4*)(xb + row*256 + w0n + sl*4);
      hi = *(const float4*)(xb + row*256 + w0n + 128 + sl*4);
    }
    // compute chunk c from cur
    float cc[4], sv[4];
#pragma unroll
    for (int j = 0; j < 4; ++j) {
      const int m = (kyv[j] * (c*16 + wq*4)) & 255;
      cc[j] = cst[m];
      sv[j] = snt[m];
    }
    const float* rp = cur + pofs;
#pragma unroll
    for (int i = 0; i < 4; ++i) {
      const int wl = wq*4 + i;
      const float4 xs4 = *(const float4*)&rp[wl*260 + tr*4];
#pragma unroll
      for (int j = 0; j < 4; ++j) {
        ar[j][0] += xs4.x * cc[j];  ai[j][0] -= xs4.x * sv[j];
        ar[j][1] += xs4.y * cc[j];  ai[j][1] -= xs4.y * sv[j];
        ar[j][2] += xs4.z * cc[j];  ai[j][2] -= xs4.z * sv[j];
        ar[j][3] += xs4.w * cc[j];  ai[j][3] -= xs4.w * sv[j];
        const float nc = cc[j]*cd[j] - sv[j]*sd[j];
        const float ns = sv[j]*cd[j] + cc[j]*sd[j];
        cc[j] = nc; sv[j] = ns;
      }
    }
    if (c < 7) {                       // stage chunk c+1 into nxt
      nxt[XEOFF(sl*4+0) + row] = lo.x + hi.x;
      nxt[XEOFF(sl*4+1) + row] = lo.y + hi.y;
      nxt[XEOFF(sl*4+2) + row] = lo.z + hi.z;
      nxt[XEOFF(sl*4+3) + row] = lo.w + hi.w;
      nxt[XOOFF(sl*4+0) + row] = lo.x - hi.x;
      nxt[XOOFF(sl*4+1) + row] = lo.y - hi.y;
      nxt[XOOFF(sl*4+2) + row] = lo.z - hi.z;
      nxt[XOOFF(sl*4+3) + row] = lo.w - hi.w;
    }
    __syncthreads();                   // ONE barrier per chunk
  }

#pragma unroll
  for (int j = 0; j < 4; ++j)
#pragma unroll
    for (int r = 0; r < 4; ++r) {
      ar[j][r] += __shfl_xor(ar[j][r], 1);
      ar[j][r] += __shfl_xor(ar[j][r], 2);
      ai[j][r] += __shfl_xor(ai[j][r], 1);
      ai[j][r] += __shfl_xor(ai[j][r], 2);
    }
  if (wq == 0) {                       // Xw planes into bufA
#pragma unroll
    for (int j = 0; j < 4; ++j) {
      const int ky = kyv[j];
      float4 sr; sr.x = ar[j][0]; sr.y = ar[j][1]; sr.z = ar[j][2]; sr.w = ar[j][3];
      float4 si; si.x = ai[j][0]; si.y = ai[j][1]; si.z = ai[j][2]; si.w = ai[j][3];
      *(float4*)&bufA[XEOFF(ky) + tr*4] = sr;
      *(float4*)&bufA[XOOFF(ky) + tr*4] = si;
    }
  }
  __syncthreads();

  // phase B: h-DFT, quarter h-range per thread
  const int ky2 = t & 15, kx = (t >> 4) & 15, hh = t >> 8;
  const float cdk = cst[kx], sdk = snt[kx];
  const int m0 = (kx * hh * 64) & 255;
  float cR = cst[m0], sR = snt[m0];
  float arr = 0.f, aii = 0.f;
  const int be = XEOFF(ky2) + hh*64;
  const int bo = XOOFF(ky2) + hh*64;
#pragma unroll 4
  for (int hq = 0; hq < 16; ++hq) {
    const float4 xr = *(const float4*)&bufA[be + hq*4];
    const float4 xi = *(const float4*)&bufA[bo + hq*4];
    {
      arr += xr.x*cR + xi.x*sR;  aii += xi.x*cR - xr.x*sR;
      const float nc = cR*cdk - sR*sdk, ns = sR*cdk + cR*sdk; cR = nc; sR = ns;
    }
    {
      arr += xr.y*cR + xi.y*sR;  aii += xi.y*cR - xr.y*sR;
      const float nc = cR*cdk - sR*sdk, ns = sR*cdk + cR*sdk; cR = nc; sR = ns;
    }
    {
      arr += xr.z*cR + xi.z*sR;  aii += xi.z*cR - xr.z*sR;
      const float nc = cR*cdk - sR*sdk, ns = sR*cdk + cR*sdk; cR = nc; sR = ns;
    }
    {
      arr += xr.w*cR + xi.w*sR;  aii += xi.w*cR - xr.w*sR;
      const float nc = cR*cdk - sR*sdk, ns = sR*cdk + cR*sdk; cR = nc; sR = ns;
    }
  }
  s2[t].x = arr; s2[t].y = aii;
  __syncthreads();
  if (t < 256) {
    float xre = s2[t].x + s2[t+256].x + s2[t+512].x + s2[t+768].x;
    float xim = s2[t].y + s2[t+256].y + s2[t+512].y + s2[t+768].y;
    ws[OF_XS_RE + img*256 + t] = xre;
    ws[OF_XS_IM + img*256 + t] = xim;
  }
}

// Stage 3: o1/o2[b,o,m] = sum_i xs[b,i,m] * (wr + i wi)[i,o,m]
__global__ __launch_bounds__(256) void k3_mix(const float* __restrict__ w1r,
    const float* __restrict__ w1i, const float* __restrict__ w2r,
    const float* __restrict__ w2i, float* __restrict__ ws) {
  const int o  = blockIdx.x;     // 0..63
  const int mc = blockIdx.y;     // 0..3
  const int t  = threadIdx.x;    // 256
  const int b  = t >> 6;
  const int m  = (mc << 6) + (t & 63);
  const float* xsr = ws + OF_XS_RE;
  const float* xsi = ws + OF_XS_IM;
  float a1r=0.f, a1i=0.f, a2r=0.f, a2i=0.f;
#pragma unroll 4
  for (int i = 0; i < NCI; ++i) {
    const float xr = xsr[((b*NCI + i) << 8) + m];
    const float xi = xsi[((b*NCI + i) << 8) + m];
    const int wi = ((i*NCO + o) << 8) + m;
    const float p = w1r[wi], q = w1i[wi], u = w2r[wi], v = w2i[wi];
    a1r += xr*p - xi*q;
    a1i += xr*q + xi*p;
    a2r += xr*u - xi*v;
    a2i += xr*v + xi*u;
  }
  const int oi = ((b*NCO + o) << 8) + m;
  ws[OF_O1_RE + oi] = a1r;
  ws[OF_O1_IM + oi] = a1i;
  ws[OF_O2_RE + oi] = a2r;
  ws[OF_O2_IM + oi] = a2i;
}

// Fused stage 4+5 (R13 structure; trig via in-kernel sincosf table).
__global__ __launch_bounds__(256) void k45_idft(const float* __restrict__ ws,
                                                float* __restrict__ out) {
  __shared__ __align__(16) float o1r[256], o1i[256], o2r[256], o2i[256];
  __shared__ float cst[256], snt[256];
  __shared__ __align__(16) float Sr[64][20], Si[64][20];
  const int t  = threadIdx.x;
  const int bo = blockIdx.x >> 2;
  const int hc = blockIdx.x & 3;

  o1r[t] = ws[OF_O1_RE + bo*256 + t];
  o1i[t] = ws[OF_O1_IM + bo*256 + t];
  o2r[t] = ws[OF_O2_RE + bo*256 + t];
  o2i[t] = ws[OF_O2_IM + bo*256 + t];
  {
    float sv_, cv_;
    sincosf(TPF * (float)t * (1.0f/256.0f), &sv_, &cv_);
    cst[t] = cv_;  snt[t] = sv_;
  }
  __syncthreads();

  const int wl = t & 31;
  float c[15], s[15], c2[15], s2[15];
#pragma unroll
  for (int k = 0; k < 15; ++k) {
    const int mi = ((k+1) * wl) & 255;
    c[k] = cst[mi];
    s[k] = snt[mi];
  }
  {
    const float R = 0.70710678118654752f;
#pragma unroll
    for (int k = 0; k < 15; ++k) {
      const int r8 = (k + 1) & 7;
      switch (r8) {
        case 0: c2[k] =  c[k];            s2[k] =  s[k];            break;
        case 1: c2[k] = (c[k]-s[k])*R;    s2[k] = (s[k]+c[k])*R;    break;
        case 2: c2[k] = -s[k];            s2[k] =  c[k];            break;
        case 3: c2[k] = -(c[k]+s[k])*R;   s2[k] = (c[k]-s[k])*R;    break;
        case 4: c2[k] = -c[k];            s2[k] = -s[k];            break;
        case 5: c2[k] = (s[k]-c[k])*R;    s2[k] = -(c[k]+s[k])*R;   break;
        case 6: c2[k] =  s[k];            s2[k] = -c[k];            break;
        default:c2[k] = (c[k]+s[k])*R;    s2[k] = (s[k]-c[k])*R;    break;
      }
    }
  }

  // ---- phase A ----
  {
    const int hl = t >> 2, kq = t & 3;
    const int h  = hc*64 + hl;
    const float chh = cst[h], shh = snt[h];
    float c1 = 1.f, s1 = 0.f;
    const int m2i = (240 * h) & 255;
    float cB = cst[m2i], sB = snt[m2i];
    float4 sr = {0.f,0.f,0.f,0.f}, si = {0.f,0.f,0.f,0.f};
    for (int j = 0; j < 16; ++j) {
      const float4 r1 = *(const float4*)&o1r[j*16 + kq*4];
      const float4 i1 = *(const float4*)&o1i[j*16 + kq*4];
      const float4 r2 = *(const float4*)&o2r[j*16 + kq*4];
      const float4 i2 = *(const float4*)&o2i[j*16 + kq*4];
      sr.x += r1.x*c1 - i1.x*s1 + r2.x*cB - i2.x*sB;
      si.x += r1.x*s1 + i1.x*c1 + r2.x*sB + i2.x*cB;
      sr.y += r1.y*c1 - i1.y*s1 + r2.y*cB - i2.y*sB;
      si.y += r1.y*s1 + i1.y*c1 + r2.y*sB + i2.y*cB;
      sr.z += r1.z*c1 - i1.z*s1 + r2.z*cB - i2.z*sB;
      si.z += r1.z*s1 + i1.z*c1 + r2.z*sB + i2.z*cB;
      sr.w += r1.w*c1 - i1.w*s1 + r2.w*cB - i2.w*sB;
      si.w += r1.w*s1 + i1.w*c1 + r2.w*sB + i2.w*cB;
      const float n1c = c1*chh - s1*shh, n1s = s1*chh + c1*shh;
      const float n2c = cB*chh - sB*shh, n2s = sB*chh + cB*shh;
      c1 = n1c; s1 = n1s; cB = n2c; sB = n2s;
    }
    *(float4*)&Sr[hl][kq*4] = sr;
    *(float4*)&Si[hl][kq*4] = si;
  }
  __syncthreads();

  // ---- phase B: row-paired, radix-4 butterfly x2 trig sets ----
  const int half = (t >> 5) & 1;
  const int wv = t >> 6;
  const float scale = 2.0f / 65536.0f;
  const size_t tilebase = ((size_t)bo*256 + hc*64) * 256;
#pragma unroll 2
  for (int pr = 0; pr < 8; ++pr) {
    const int hl = wv*16 + pr*2 + half;
    const float4 a0 = *(const float4*)&Sr[hl][0];
    const float4 a1 = *(const float4*)&Sr[hl][4];
    const float4 a2 = *(const float4*)&Sr[hl][8];
    const float4 a3 = *(const float4*)&Sr[hl][12];
    const float4 b0 = *(const float4*)&Si[hl][0];
    const float4 b1 = *(const float4*)&Si[hl][4];
    const float4 b2 = *(const float4*)&Si[hl][8];
    const float4 b3 = *(const float4*)&Si[hl][12];
    const float re[16] = {a0.x,a0.y,a0.z,a0.w, a1.x,a1.y,a1.z,a1.w,
                          a2.x,a2.y,a2.z,a2.w, a3.x,a3.y,a3.z,a3.w};
    const float im[16] = {b0.x,b0.y,b0.z,b0.w, b1.x,b1.y,b1.z,b1.w,
                          b2.x,b2.y,b2.z,b2.w, b3.x,b3.y,b3.z,b3.w};
    const size_t ob = tilebase + (size_t)hl*256;

#pragma unroll
    for (int g = 0; g < 2; ++g) {
      const float* cc = g ? c2 : c;
      const float* ss = g ? s2 : s;
      float PA = 0.5f * re[0];
      float PB = 0.f, PC = 0.f, PD = 0.f, QB = 0.f, QD = 0.f;
#pragma unroll
      for (int k = 0; k < 15; ++k) {
        const int ky = k + 1;
        const float R = re[ky], I = im[ky];
        const int cls = ky & 3;
        if (cls == 0)      PA += R*cc[k] - I*ss[k];
        else if (cls == 1) { PB += R*cc[k] - I*ss[k];  QB += R*ss[k] + I*cc[k]; }
        else if (cls == 2) PC += R*cc[k] - I*ss[k];
        else               { PD += R*cc[k] - I*ss[k];  QD += R*ss[k] + I*cc[k]; }
      }
      const float T1 = PA + PC, T2 = PB + PD;
      const float T3 = PA - PC, T4 = QB - QD;
      const int cb = wl + g*32;
      out[ob + cb]       = (T1 + T2) * scale;
      out[ob + cb + 64]  = (T3 - T4) * scale;
      out[ob + cb + 128] = (T1 - T2) * scale;
      out[ob + cb + 192] = (T3 + T4) * scale;
    }
  }
}

extern "C" void kernel_launch(void* const* d_in, const int* in_sizes, int n_in,
                              void* d_out, int out_size, void* d_ws, size_t ws_size,
                              hipStream_t stream) {
  const float* x   = (const float*)d_in[0];
  const float* w1r = (const float*)d_in[1];
  const float* w1i = (const float*)d_in[2];
  const float* w2r = (const float*)d_in[3];
  const float* w2i = (const float*)d_in[4];
  float* out = (float*)d_out;
  float* ws  = (float*)d_ws;

  hipLaunchKernelGGL(k12_dft,  dim3(256),   dim3(1024), 0, stream, x, ws);
  hipLaunchKernelGGL(k3_mix,   dim3(64, 4), dim3(256),  0, stream, w1r, w1i, w2r, w2i, ws);
  hipLaunchKernelGGL(k45_idft, dim3(1024),  dim3(256),  0, stream, ws, out);
}